// Round 1
// baseline (371.306 us; speedup 1.0000x reference)
//
#include <hip/hip_runtime.h>
#include <math.h>

#define C_LEN 2048
#define OUTD  1536
#define NPIX  32768
#define BLK   256

// XOR swizzle: bijective within [0,2048), keeps 32-aligned groups permuted
// within themselves -> consecutive-lane accesses stay conflict-free.
__device__ __forceinline__ int SWZ(int idx) {
    return idx ^ ((idx >> 5) & 31);
}

// Stockham mixed-radix FFT of 2048 complex values in LDS (SoA re/im),
// ping-pong (r0,i0)<->(r1,i1). Stages: radix-2 (m=1) then radix-4 x5
// (m=2,8,32,128,512). DIR=-1 forward, DIR=+1 inverse (unnormalized).
// Data starts swizzled in r0/i0 and ends in r0/i0 (6 swaps = even).
template<int DIR>
__device__ void fft2048(float* r0, float* i0, float* r1, float* i1, int t) {
    float *sr = r0, *si = i0, *dr = r1, *di = i1;
    const float TW = (float)DIR * 6.283185307179586f / 2048.0f;
    const float FD = (float)DIR;

    // ---- stage 1: radix-2, m=1, l*m=1024 ----
    __syncthreads();
    #pragma unroll
    for (int b = 0; b < 4; ++b) {
        int t2 = t + b * BLK;                 // butterfly id in [0,1024)
        float ar = sr[SWZ(t2)],        ai = si[SWZ(t2)];
        float br = sr[SWZ(t2 + 1024)], bi = si[SWZ(t2 + 1024)];
        float sn, cs;
        __sincosf(TW * (float)t2, &sn, &cs);  // w = exp(DIR*2*pi*i*t2/2048)
        float vr = ar - br, vi = ai - bi;
        int w0 = 2 * t2;
        dr[SWZ(w0)]     = ar + br;
        di[SWZ(w0)]     = ai + bi;
        dr[SWZ(w0 + 1)] = cs * vr - sn * vi;
        di[SWZ(w0 + 1)] = cs * vi + sn * vr;
    }
    { float* tp; tp = sr; sr = dr; dr = tp; tp = si; si = di; di = tp; }

    // ---- 5 radix-4 stages: m = 2,8,32,128,512, l*m = 512 ----
    #pragma unroll
    for (int m = 2; m <= 512; m *= 4) {
        __syncthreads();
        #pragma unroll
        for (int b = 0; b < 2; ++b) {
            int t2 = t + b * BLK;             // butterfly id in [0,512)
            int jm = t2 & ~(m - 1);           // j*m
            float a0r = sr[SWZ(t2)],        a0i = si[SWZ(t2)];
            float a1r = sr[SWZ(t2 + 512)],  a1i = si[SWZ(t2 + 512)];
            float a2r = sr[SWZ(t2 + 1024)], a2i = si[SWZ(t2 + 1024)];
            float a3r = sr[SWZ(t2 + 1536)], a3i = si[SWZ(t2 + 1536)];
            float s0r = a0r + a2r, s0i = a0i + a2i;
            float d0r = a0r - a2r, d0i = a0i - a2i;
            float s1r = a1r + a3r, s1i = a1i + a3i;
            float d1r = a1r - a3r, d1i = a1i - a3i;
            // A0 = s0+s1, A2 = s0-s1, A1 = d0 + DIR*i*d1, A3 = d0 - DIR*i*d1
            float A0r = s0r + s1r, A0i = s0i + s1i;
            float A2r = s0r - s1r, A2i = s0i - s1i;
            float A1r = d0r - FD * d1i, A1i = d0i + FD * d1r;
            float A3r = d0r + FD * d1i, A3i = d0i - FD * d1r;
            // twiddles w1 = exp(DIR*2*pi*i*jm/2048), w2=w1^2, w3=w1*w2
            float s1w, c1w;
            __sincosf(TW * (float)jm, &s1w, &c1w);
            float c2w = c1w * c1w - s1w * s1w, s2w = 2.0f * c1w * s1w;
            float c3w = c1w * c2w - s1w * s2w, s3w = c1w * s2w + s1w * c2w;
            int wb = t2 + 3 * jm;             // k + 4*j*m
            dr[SWZ(wb)]         = A0r;
            di[SWZ(wb)]         = A0i;
            dr[SWZ(wb + m)]     = c1w * A1r - s1w * A1i;
            di[SWZ(wb + m)]     = c1w * A1i + s1w * A1r;
            dr[SWZ(wb + 2 * m)] = c2w * A2r - s2w * A2i;
            di[SWZ(wb + 2 * m)] = c2w * A2i + s2w * A2r;
            dr[SWZ(wb + 3 * m)] = c3w * A3r - s3w * A3i;
            di[SWZ(wb + 3 * m)] = c3w * A3i + s3w * A3r;
        }
        { float* tp; tp = sr; sr = dr; dr = tp; tp = si; si = di; di = tp; }
    }
    __syncthreads();
    // 6 swaps total -> result is back in r0/i0
}

// Kernel 1: Wf = fft(W1 .* W2), one block.
__global__ __launch_bounds__(BLK)
void wfft_kernel(const float* __restrict__ w1, const float* __restrict__ w2,
                 float* __restrict__ wfr, float* __restrict__ wfi) {
    __shared__ float r0[C_LEN], i0[C_LEN], r1[C_LEN], i1[C_LEN];
    int t = threadIdx.x;
    #pragma unroll
    for (int k = 0; k < 8; ++k) {
        int e = t + k * BLK;
        r0[SWZ(e)] = w1[e] * w2[e];
        i0[SWZ(e)] = 0.0f;
    }
    fft2048<-1>(r0, i0, r1, i1, t);
    #pragma unroll
    for (int k = 0; k < 8; ++k) {
        int e = t + k * BLK;
        wfr[e] = r0[SWZ(e)];
        wfi[e] = i0[SWZ(e)];
    }
}

// Kernel 2: per pixel: fft(x) -> *Wf -> ifft -> real part, first 1536.
__global__ __launch_bounds__(BLK)
void conv_kernel(const float* __restrict__ x,
                 const float* __restrict__ wfr, const float* __restrict__ wfi,
                 float* __restrict__ out) {
    __shared__ float r0[C_LEN], i0[C_LEN], r1[C_LEN], i1[C_LEN];
    int t = threadIdx.x;
    size_t pix = blockIdx.x;
    const float* xp = x + pix * (size_t)C_LEN;

    // load 2048 f32 coalesced (float4), zero imaginary
    #pragma unroll
    for (int k = 0; k < 2; ++k) {
        int e = (t + k * BLK) * 4;
        float4 v = *reinterpret_cast<const float4*>(xp + e);
        r0[SWZ(e)]     = v.x;
        r0[SWZ(e + 1)] = v.y;
        r0[SWZ(e + 2)] = v.z;
        r0[SWZ(e + 3)] = v.w;
        i0[SWZ(e)]     = 0.0f;
        i0[SWZ(e + 1)] = 0.0f;
        i0[SWZ(e + 2)] = 0.0f;
        i0[SWZ(e + 3)] = 0.0f;
    }

    fft2048<-1>(r0, i0, r1, i1, t);

    // pointwise multiply by Wf (L2-resident)
    #pragma unroll
    for (int k = 0; k < 8; ++k) {
        int e = t + k * BLK;
        int se = SWZ(e);
        float xr = r0[se], xi = i0[se];
        float wr = wfr[e], wi = wfi[e];
        r0[se] = xr * wr - xi * wi;
        i0[se] = xr * wi + xi * wr;
    }

    fft2048<1>(r0, i0, r1, i1, t);   // leading __syncthreads covers the multiply

    // write real part of first 1536, scaled by 1/N
    #pragma unroll
    for (int k = 0; k < 6; ++k) {
        int c = t + k * BLK;
        out[pix * (size_t)OUTD + c] = r0[SWZ(c)] * (1.0f / 2048.0f);
    }
}

extern "C" void kernel_launch(void* const* d_in, const int* in_sizes, int n_in,
                              void* d_out, int out_size, void* d_ws, size_t ws_size,
                              hipStream_t stream) {
    const float* x  = (const float*)d_in[0];
    const float* w1 = (const float*)d_in[1];
    const float* w2 = (const float*)d_in[2];
    float* out = (float*)d_out;
    float* wfr = (float*)d_ws;          // 2048 f32
    float* wfi = wfr + C_LEN;           // 2048 f32

    hipLaunchKernelGGL(wfft_kernel, dim3(1), dim3(BLK), 0, stream, w1, w2, wfr, wfi);
    hipLaunchKernelGGL(conv_kernel, dim3(NPIX), dim3(BLK), 0, stream, x, wfr, wfi, out);
}

// Round 2
// 169.467 us; speedup vs baseline: 2.1910x; 2.1910x over previous
//
#include <hip/hip_runtime.h>
#include <math.h>

#define C_LEN 2048
#define HALF  1024
#define OUTD  1536
#define NPIX  32768
#define BLK   256

// XOR swizzle: bijective within 32-element blocks; makes stride-pattern LDS
// writes of the Stockham stages (mostly) bank-conflict-free.
__device__ __forceinline__ int SWZ(int idx) { return idx ^ ((idx >> 5) & 31); }

// ===================== 2048-pt FFT (precompute kernel only) =================
// Stockham: radix-2 (m=1) then radix-4 x5 (m=2..512). Precise sincosf (runs
// once, 1 block). Data swizzled in r0/i0, result back in r0/i0 (6 swaps).
template<int DIR>
__device__ void fft2048(float* r0, float* i0, float* r1, float* i1, int t) {
    float *sr = r0, *si = i0, *dr = r1, *di = i1;
    const float TW = (float)DIR * 6.283185307179586f / 2048.0f;
    const float FD = (float)DIR;

    __syncthreads();
    #pragma unroll
    for (int b = 0; b < 4; ++b) {
        int t2 = t + b * BLK;
        float ar = sr[SWZ(t2)],        ai = si[SWZ(t2)];
        float br = sr[SWZ(t2 + 1024)], bi = si[SWZ(t2 + 1024)];
        float sn, cs;
        sincosf(TW * (float)t2, &sn, &cs);
        float vr = ar - br, vi = ai - bi;
        int w0 = 2 * t2;
        dr[SWZ(w0)]     = ar + br;
        di[SWZ(w0)]     = ai + bi;
        dr[SWZ(w0 + 1)] = cs * vr - sn * vi;
        di[SWZ(w0 + 1)] = cs * vi + sn * vr;
    }
    { float* tp; tp = sr; sr = dr; dr = tp; tp = si; si = di; di = tp; }

    #pragma unroll
    for (int m = 2; m <= 512; m *= 4) {
        __syncthreads();
        #pragma unroll
        for (int b = 0; b < 2; ++b) {
            int t2 = t + b * BLK;
            int jm = t2 & ~(m - 1);
            float a0r = sr[SWZ(t2)],        a0i = si[SWZ(t2)];
            float a1r = sr[SWZ(t2 + 512)],  a1i = si[SWZ(t2 + 512)];
            float a2r = sr[SWZ(t2 + 1024)], a2i = si[SWZ(t2 + 1024)];
            float a3r = sr[SWZ(t2 + 1536)], a3i = si[SWZ(t2 + 1536)];
            float s0r = a0r + a2r, s0i = a0i + a2i;
            float d0r = a0r - a2r, d0i = a0i - a2i;
            float s1r = a1r + a3r, s1i = a1i + a3i;
            float d1r = a1r - a3r, d1i = a1i - a3i;
            float A0r = s0r + s1r, A0i = s0i + s1i;
            float A2r = s0r - s1r, A2i = s0i - s1i;
            float A1r = d0r - FD * d1i, A1i = d0i + FD * d1r;
            float A3r = d0r + FD * d1i, A3i = d0i - FD * d1r;
            float s1w, c1w;
            sincosf(TW * (float)jm, &s1w, &c1w);
            float c2w = c1w * c1w - s1w * s1w, s2w = 2.0f * c1w * s1w;
            float c3w = c1w * c2w - s1w * s2w, s3w = c1w * s2w + s1w * c2w;
            int wb = t2 + 3 * jm;
            dr[SWZ(wb)]         = A0r;
            di[SWZ(wb)]         = A0i;
            dr[SWZ(wb + m)]     = c1w * A1r - s1w * A1i;
            di[SWZ(wb + m)]     = c1w * A1i + s1w * A1r;
            dr[SWZ(wb + 2 * m)] = c2w * A2r - s2w * A2i;
            di[SWZ(wb + 2 * m)] = c2w * A2i + s2w * A2r;
            dr[SWZ(wb + 3 * m)] = c3w * A3r - s3w * A3i;
            di[SWZ(wb + 3 * m)] = c3w * A3i + s3w * A3r;
        }
        { float* tp; tp = sr; sr = dr; dr = tp; tp = si; si = di; di = tp; }
    }
    __syncthreads();
}

// Precompute kernel: Wf = fft2048(w1.*w2); then fold the real-FFT unpack,
// pointwise multiply, and repack into two complex tables U,V of length 1024:
//   Z'[k] = (Z[k]+conj(Z[-k]))*U[k] + (Z[k]-conj(Z[-k]))*V[k]
//   U = S + i*e^{+i th}*Dw,  V = S - i*e^{-i th}*Dw,  th = 2*pi*k/2048
//   S = (Wf[k]+Wf[k+1024])/4096,  Dw = (Wf[k]-Wf[k+1024])/4096
// (1/4096 = unpack/repack halves * 1/1024 inverse-FFT normalization)
__global__ __launch_bounds__(BLK)
void uv_kernel(const float* __restrict__ w1, const float* __restrict__ w2,
               float4* __restrict__ uv) {
    __shared__ float r0[C_LEN], i0[C_LEN], r1[C_LEN], i1[C_LEN];
    int t = threadIdx.x;
    #pragma unroll
    for (int k = 0; k < 8; ++k) {
        int e = t + k * BLK;
        r0[SWZ(e)] = w1[e] * w2[e];
        i0[SWZ(e)] = 0.0f;
    }
    fft2048<-1>(r0, i0, r1, i1, t);
    #pragma unroll
    for (int b = 0; b < 4; ++b) {
        int k = t + b * BLK;
        float w1r = r0[SWZ(k)],        w1i = i0[SWZ(k)];
        float w2r = r0[SWZ(k + 1024)], w2i = i0[SWZ(k + 1024)];
        float Sr = (w1r + w2r) * (1.0f / 4096.0f);
        float Si = (w1i + w2i) * (1.0f / 4096.0f);
        float Dr = (w1r - w2r) * (1.0f / 4096.0f);
        float Di = (w1i - w2i) * (1.0f / 4096.0f);
        float sn, cs;
        sincosf((6.283185307179586f / 2048.0f) * (float)k, &sn, &cs);
        float Er = cs * Dr - sn * Di, Ei = cs * Di + sn * Dr;  // e^{+i th} * Dw
        float Fr = cs * Dr + sn * Di, Fi = cs * Di - sn * Dr;  // e^{-i th} * Dw
        // U = S + i*E = (Sr - Ei, Si + Er);  V = S - i*F = (Sr + Fi, Si - Fr)
        uv[k] = make_float4(Sr - Ei, Si + Er, Sr + Fi, Si - Fr);
    }
}

// ===================== 1024-pt FFT (per-pixel) ==============================
// Pure radix-4 Stockham (1024 = 4^5), one butterfly per thread per stage.
// Twiddles from LDS table: w1 = (twc[jm], DIR*tws[jm]); w2 = w1^2; w3 = w1*w2.
// 5 swaps -> result lands in r1/i1.
template<int DIR>
__device__ __forceinline__ void fft1024(float* r0, float* i0, float* r1, float* i1,
                                        const float* twc, const float* tws, int t) {
    float *sr = r0, *si = i0, *dr = r1, *di = i1;
    const float FD = (float)DIR;
    #pragma unroll
    for (int m = 1; m <= 256; m *= 4) {
        __syncthreads();
        int jm = t & ~(m - 1);
        int rs0 = SWZ(t), rs1 = SWZ(t + 256), rs2 = SWZ(t + 512), rs3 = SWZ(t + 768);
        float a0r = sr[rs0], a0i = si[rs0];
        float a1r = sr[rs1], a1i = si[rs1];
        float a2r = sr[rs2], a2i = si[rs2];
        float a3r = sr[rs3], a3i = si[rs3];
        float s0r = a0r + a2r, s0i = a0i + a2i;
        float d0r = a0r - a2r, d0i = a0i - a2i;
        float s1r = a1r + a3r, s1i = a1i + a3i;
        float d1r = a1r - a3r, d1i = a1i - a3i;
        float A0r = s0r + s1r, A0i = s0i + s1i;
        float A2r = s0r - s1r, A2i = s0i - s1i;
        float A1r = d0r - FD * d1i, A1i = d0i + FD * d1r;
        float A3r = d0r + FD * d1i, A3i = d0i - FD * d1r;
        float c1 = twc[jm], s1w = FD * tws[jm];
        float c2 = c1 * c1 - s1w * s1w, s2w = 2.0f * c1 * s1w;
        float c3 = c1 * c2 - s1w * s2w, s3w = c1 * s2w + s1w * c2;
        int wb = t + 3 * jm;
        int ws0 = SWZ(wb), ws1 = SWZ(wb + m), ws2 = SWZ(wb + 2 * m), ws3 = SWZ(wb + 3 * m);
        dr[ws0] = A0r;
        di[ws0] = A0i;
        dr[ws1] = c1 * A1r - s1w * A1i;
        di[ws1] = c1 * A1i + s1w * A1r;
        dr[ws2] = c2 * A2r - s2w * A2i;
        di[ws2] = c2 * A2i + s2w * A2r;
        dr[ws3] = c3 * A3r - s3w * A3i;
        di[ws3] = c3 * A3i + s3w * A3r;
        float* tp; tp = sr; sr = dr; dr = tp; tp = si; si = di; di = tp;
    }
    __syncthreads();
}

// Per pixel: pack x as 1024 complex -> FFT -> fused (unpack*Wf*repack) via
// U,V tables -> inverse FFT -> interleaved real outputs, first 1536.
__global__ __launch_bounds__(BLK)
void conv_kernel(const float* __restrict__ x, const float4* __restrict__ uv,
                 float2* __restrict__ out) {
    __shared__ float r0[HALF], i0[HALF], r1[HALF], i1[HALF];
    __shared__ float twc[256], tws[256];
    int t = threadIdx.x;
    {
        float sn, cs;
        sincosf((6.283185307179586f / 1024.0f) * (float)t, &sn, &cs);
        twc[t] = cs;
        tws[t] = sn;
    }
    size_t pix = blockIdx.x;
    const float4* xp = reinterpret_cast<const float4*>(x + pix * (size_t)C_LEN);
    #pragma unroll
    for (int b = 0; b < 2; ++b) {
        int e = t + b * BLK;       // float4 index in [0,512)
        float4 v = xp[e];
        int n = 2 * e;             // complex index: z[n] = x[2n] + i x[2n+1]
        int sA = SWZ(n), sB = SWZ(n + 1);
        r0[sA] = v.x; i0[sA] = v.y;
        r0[sB] = v.z; i0[sB] = v.w;
    }

    fft1024<-1>(r0, i0, r1, i1, twc, tws, t);   // Z in r1/i1

    // middle: Z' = (Z[k]+conj(Z[-k]))*U + (Z[k]-conj(Z[-k]))*V -> r0/i0
    #pragma unroll
    for (int b = 0; b < 4; ++b) {
        int k = t + b * BLK;
        int k2 = (HALF - k) & (HALF - 1);
        int sa = SWZ(k), sb = SWZ(k2);
        float Zar = r1[sa], Zai = i1[sa];
        float Zbr = r1[sb], Zbi = -i1[sb];
        float Ar = Zar + Zbr, Ai = Zai + Zbi;
        float Br = Zar - Zbr, Bi = Zai - Zbi;
        float4 u = uv[k];
        r0[sa] = Ar * u.x - Ai * u.y + Br * u.z - Bi * u.w;
        i0[sa] = Ar * u.y + Ai * u.x + Br * u.w + Bi * u.z;
    }

    fft1024<1>(r0, i0, r1, i1, twc, tws, t);    // z' in r1/i1 (leading barrier inside)

    // y[2n] = Re z'[n], y[2n+1] = Im z'[n]; keep n < 768 (OUTD=1536).
    #pragma unroll
    for (int b = 0; b < 3; ++b) {
        int n = t + b * BLK;
        int s = SWZ(n);
        out[pix * (size_t)(OUTD / 2) + n] = make_float2(r1[s], i1[s]);
    }
}

extern "C" void kernel_launch(void* const* d_in, const int* in_sizes, int n_in,
                              void* d_out, int out_size, void* d_ws, size_t ws_size,
                              hipStream_t stream) {
    const float* x  = (const float*)d_in[0];
    const float* w1 = (const float*)d_in[1];
    const float* w2 = (const float*)d_in[2];
    float2* out = (float2*)d_out;
    float4* uv  = (float4*)d_ws;          // 1024 float4 = 16 KB

    hipLaunchKernelGGL(uv_kernel, dim3(1), dim3(BLK), 0, stream, w1, w2, uv);
    hipLaunchKernelGGL(conv_kernel, dim3(NPIX), dim3(BLK), 0, stream, x, uv, out);
}